// Round 1
// baseline (242.585 us; speedup 1.0000x reference)
//
#include <hip/hip_runtime.h>

// x: (B=32, H=256, W=256, C=16) float32, row-major.
// p[h][w] = mean over (b, c) of x[b][h][w][c]  (512 values)
// out = p >= 0.25 ? x*0.25/p : 1 - (0.75/(1-p))*(1-x)  ==  a*x + d
//
// Block = 256 threads (4 waves), handles one h and a 16-wide w-tile:
//   tile slice per b = 16 w * 16 c = 256 floats = 1 KiB contiguous.
//   Wave wv reads b = 4k + wv as 64 coalesced float4s, k = 0..7.
//   Thread (lane l) holds x[b][w'=l>>2][c=(l&3)*4 .. +3] for its 8 b's.
// Reduction: thread-local sum -> shfl_xor(1,2) over 4 lanes sharing w'
//   -> 4x16 LDS cross-wave sum -> p per w'.
// Then fused elementwise apply + float4 store. x read exactly once.

#define ALPHA 0.25f

__global__ __launch_bounds__(256) void rescale_prob_mask_kernel(
    const float* __restrict__ x, float* __restrict__ out) {
  constexpr long F4_PER_B = 256L * 256 * 16 / 4;  // 262144 float4 per batch

  const int tile = blockIdx.x;        // 0..4095
  const int h    = tile >> 4;
  const int w0   = (tile & 15) << 4;
  const long tile_base_f4 = (((long)h * 256 + w0) * 16) >> 2;

  const int t    = threadIdx.x;
  const int lane = t & 63;
  const int wv   = t >> 6;

  const float4* __restrict__ p4 =
      (const float4*)x + tile_base_f4 + (long)wv * F4_PER_B + lane;
  float4* __restrict__ o4 =
      (float4*)out + tile_base_f4 + (long)wv * F4_PER_B + lane;

  float4 v[8];
#pragma unroll
  for (int k = 0; k < 8; ++k) {
    v[k] = p4[(long)k * 4 * F4_PER_B];  // b = 4k + wv
  }

  // thread-local sum over its 8 b's and 4 c's
  float s = 0.0f;
#pragma unroll
  for (int k = 0; k < 8; ++k) {
    s += (v[k].x + v[k].y) + (v[k].z + v[k].w);
  }
  // reduce over the 4 lanes sharing w' = lane>>2 (covers all 16 c)
  s += __shfl_xor(s, 1);
  s += __shfl_xor(s, 2);

  // cross-wave reduction: 4 waves x 16 w'
  __shared__ float lds[4][16];
  const int wp = lane >> 2;
  if ((lane & 3) == 0) lds[wv][wp] = s;
  __syncthreads();
  const float psum = (lds[0][wp] + lds[1][wp]) + (lds[2][wp] + lds[3][wp]);
  const float p = psum * (1.0f / 512.0f);

  // out = a*x + d
  float a, d;
  if (p >= ALPHA) {
    a = ALPHA / p;
    d = 0.0f;
  } else {
    const float beta = (1.0f - ALPHA) / (1.0f - p);
    a = beta;
    d = 1.0f - beta;
  }

#pragma unroll
  for (int k = 0; k < 8; ++k) {
    float4 r;
    r.x = a * v[k].x + d;
    r.y = a * v[k].y + d;
    r.z = a * v[k].z + d;
    r.w = a * v[k].w + d;
    o4[(long)k * 4 * F4_PER_B] = r;
  }
}

extern "C" void kernel_launch(void* const* d_in, const int* in_sizes, int n_in,
                              void* d_out, int out_size, void* d_ws, size_t ws_size,
                              hipStream_t stream) {
  const float* x = (const float*)d_in[0];
  float* out = (float*)d_out;
  // 256 h * 16 w-tiles = 4096 blocks
  rescale_prob_mask_kernel<<<dim3(4096), dim3(256), 0, stream>>>(x, out);
}

// Round 2
// 239.641 us; speedup vs baseline: 1.0123x; 1.0123x over previous
//
#include <hip/hip_runtime.h>

// x: (B=32, H=256, W=256, C=16) float32, row-major.
// p[h][w] = mean over (b, c) of x[b][h][w][c]  (512 values)
// out = p >= 0.25 ? x*0.25/p : 1 - (0.75/(1-p))*(1-x)  ==  a*x + d
//
// Block = 256 threads (4 waves), one h and a 16-wide w-tile:
//   tile slice per b = 16 w * 16 c = 256 floats = 1 KiB contiguous.
//   Wave wv reads b = 4k + wv as 64 coalesced float4s, k = 0..7.
// Reduction: thread-local sum -> shfl_xor(1,2) over the 4 lanes sharing w'
//   -> 4x16 LDS cross-wave sum -> p per w'.
// KEY (round 2): asm-pin the 8 float4 in VGPRs after the barrier so the
// compiler cannot re-load x (round-1 disasm evidence: VGPR_Count=28 => it
// rematerialized the loads, reading x twice). Nontemporal stores keep the
// write stream out of L2/L3 so reads keep the cache bandwidth.

#define ALPHA 0.25f

typedef float v4f __attribute__((ext_vector_type(4)));

__global__ __launch_bounds__(256) void rescale_prob_mask_kernel(
    const float* __restrict__ x, float* __restrict__ out) {
  constexpr long F4_PER_B = 256L * 256 * 16 / 4;  // 262144 float4 per batch

  const int tile = blockIdx.x;        // 0..4095
  const int h    = tile >> 4;
  const int w0   = (tile & 15) << 4;
  const long tile_base_f4 = (((long)h * 256 + w0) * 16) >> 2;

  const int t    = threadIdx.x;
  const int lane = t & 63;
  const int wv   = t >> 6;

  const float4* __restrict__ p4 =
      (const float4*)x + tile_base_f4 + (long)wv * F4_PER_B + lane;
  float* __restrict__ obase =
      (float*)out + 4 * (tile_base_f4 + (long)wv * F4_PER_B + lane);

  float4 v[8];
#pragma unroll
  for (int k = 0; k < 8; ++k) {
    v[k] = p4[(long)k * 4 * F4_PER_B];  // b = 4k + wv
  }

  // thread-local sum over its 8 b's and 4 c's
  float s = 0.0f;
#pragma unroll
  for (int k = 0; k < 8; ++k) {
    s += (v[k].x + v[k].y) + (v[k].z + v[k].w);
  }
  // reduce over the 4 lanes sharing w' = lane>>2 (covers all 16 c)
  s += __shfl_xor(s, 1);
  s += __shfl_xor(s, 2);

  // cross-wave reduction: 4 waves x 16 w'
  __shared__ float lds[4][16];
  const int wp = lane >> 2;
  if ((lane & 3) == 0) lds[wv][wp] = s;
  __syncthreads();
  const float psum = (lds[0][wp] + lds[1][wp]) + (lds[2][wp] + lds[3][wp]);
  const float p = psum * (1.0f / 512.0f);

  // out = a*x + d
  float a, d;
  if (p >= ALPHA) {
    a = ALPHA / p;
    d = 0.0f;
  } else {
    const float beta = (1.0f - ALPHA) / (1.0f - p);
    a = beta;
    d = 1.0f - beta;
  }

  // Pin v[] in VGPRs: after this, the compiler cannot re-derive v from x,
  // so it must keep the loaded values live across the barrier (no 2nd read).
#pragma unroll
  for (int k = 0; k < 8; ++k) {
    asm volatile("" : "+v"(v[k].x), "+v"(v[k].y), "+v"(v[k].z), "+v"(v[k].w));
  }

#pragma unroll
  for (int k = 0; k < 8; ++k) {
    v4f r;
    r.x = fmaf(a, v[k].x, d);
    r.y = fmaf(a, v[k].y, d);
    r.z = fmaf(a, v[k].z, d);
    r.w = fmaf(a, v[k].w, d);
    __builtin_nontemporal_store(
        r, (v4f*)(obase + (long)k * 4 * F4_PER_B * 4));
  }
}

extern "C" void kernel_launch(void* const* d_in, const int* in_sizes, int n_in,
                              void* d_out, int out_size, void* d_ws, size_t ws_size,
                              hipStream_t stream) {
  const float* x = (const float*)d_in[0];
  float* out = (float*)d_out;
  // 256 h * 16 w-tiles = 4096 blocks
  rescale_prob_mask_kernel<<<dim3(4096), dim3(256), 0, stream>>>(x, out);
}